// Round 3
// baseline (200.360 us; speedup 1.0000x reference)
//
#include <hip/hip_runtime.h>
#include <hip/hip_bf16.h>

typedef __bf16 bf16;
typedef __bf16 bf16x4 __attribute__((ext_vector_type(4)));
typedef __bf16 bf16x8 __attribute__((ext_vector_type(8)));
typedef float  f32x4  __attribute__((ext_vector_type(4)));

extern "C" __device__ float __ocml_exp2_f32(float);

#define S_  1024
#define D_  64
#define BQ  64           // queries per block: 4 waves x 16
#define BK  64           // keys per tile
#define KT  (S_/BK)      // 16
#define QT  (S_/BQ)      // 16
#define LD  72           // LDS row stride (bf16): 144B, 16B-aligned, phase-clean

// ks region is REUSED as the per-wave P buffer after QK^T (ks dead then):
//   wave w owns rows [16w, 16w+16) -> P[q][key], same LD stride.
__global__ __launch_bounds__(256, 8)
void fa_fwd(const float* __restrict__ Q, const float* __restrict__ K,
            const float* __restrict__ V, const int* __restrict__ mask,
            float* __restrict__ O)
{
    __shared__ bf16 ks[BK][LD];   // K tile [key][d] / later P tiles
    __shared__ bf16 vt[D_][LD];   // V tile transposed [d][key]

    const int tid  = threadIdx.x;
    const int lane = tid & 63;
    const int w    = tid >> 6;
    const int quad = (lane >> 4) & 3;
    const int l16  = lane & 15;

    // XCD swizzle: all 16 q-tiles of one bh on one XCD (bid%8 round-robin)
    const int bid   = blockIdx.x;
    const int xcd   = bid & 7;
    const int rnd   = bid >> 3;                  // 0..255
    const int qtile = rnd & 15;
    const int bh    = ((rnd >> 4) << 3) | xcd;   // 0..127
    const int b     = bh >> 4;                   // H = 16
    const size_t base = (size_t)bh * (S_ * D_);
    const int qbase = qtile * BQ + w * 16;

    // fold softmax scale and log2e into Q: exp(s/8) == exp2(s * log2e/8)
    const float qscale = (mask[b] != 0) ? 0.0f : 0.180336880111f;

    // ---- Q fragments direct from global: lane l16 = query row, k = quad*8+j ----
    bf16x8 qf[2];
    {
        const float* qp = Q + base + (size_t)(qbase + l16) * D_ + quad * 8;
        #pragma unroll
        for (int h = 0; h < 2; ++h) {
            float4 a = *(const float4*)(qp + h * 32);
            float4 c = *(const float4*)(qp + h * 32 + 4);
            bf16x8 f;
            f[0] = (bf16)(a.x * qscale); f[1] = (bf16)(a.y * qscale);
            f[2] = (bf16)(a.z * qscale); f[3] = (bf16)(a.w * qscale);
            f[4] = (bf16)(c.x * qscale); f[5] = (bf16)(c.y * qscale);
            f[6] = (bf16)(c.z * qscale); f[7] = (bf16)(c.w * qscale);
            qf[h] = f;
        }
    }

    f32x4 acc[4];
    #pragma unroll
    for (int dt = 0; dt < 4; ++dt) acc[dt] = (f32x4){0.f, 0.f, 0.f, 0.f};
    float lsum = 0.f;

    // V-transpose lane map: vkq spans 16 values within a wave -> uniform banks
    const int vkq = (tid >> 2) & 15;        // 4-key group 0..15
    const int vc4 = (tid & 3) + 4 * w;      // d-chunk 0..15

    for (int kt = 0; kt < KT; ++kt) {
        __syncthreads();   // prior tile: vt reads + P reads (in ks region) done
        // ---- stage K: 64x64 fp32 -> bf16 row-major (b64 writes, 2-way max) ----
        const float4* gk = (const float4*)(K + base + (size_t)kt * (BK * D_));
        #pragma unroll
        for (int it = 0; it < 4; ++it) {
            int i = it * 256 + tid;
            int row = i >> 4, c4 = i & 15;
            float4 kv = gk[i];
            bf16x4 hk = {(bf16)kv.x, (bf16)kv.y, (bf16)kv.z, (bf16)kv.w};
            *(bf16x4*)&ks[row][c4 * 4] = hk;
        }
        // ---- stage V transposed: in-register 4x4 pack, uniform-bank b64 writes ----
        const float4* gv = (const float4*)(V + base + (size_t)kt * (BK * D_));
        {
            float4 v0 = gv[(vkq * 4 + 0) * 16 + vc4];
            float4 v1 = gv[(vkq * 4 + 1) * 16 + vc4];
            float4 v2 = gv[(vkq * 4 + 2) * 16 + vc4];
            float4 v3 = gv[(vkq * 4 + 3) * 16 + vc4];
            bf16x4 t0 = {(bf16)v0.x, (bf16)v1.x, (bf16)v2.x, (bf16)v3.x};
            bf16x4 t1 = {(bf16)v0.y, (bf16)v1.y, (bf16)v2.y, (bf16)v3.y};
            bf16x4 t2 = {(bf16)v0.z, (bf16)v1.z, (bf16)v2.z, (bf16)v3.z};
            bf16x4 t3 = {(bf16)v0.w, (bf16)v1.w, (bf16)v2.w, (bf16)v3.w};
            *(bf16x4*)&vt[vc4 * 4 + 0][vkq * 4] = t0;
            *(bf16x4*)&vt[vc4 * 4 + 1][vkq * 4] = t1;
            *(bf16x4*)&vt[vc4 * 4 + 2][vkq * 4] = t2;
            *(bf16x4*)&vt[vc4 * 4 + 3][vkq * 4] = t3;
        }
        __syncthreads();

        // ---- S^T = K . Q^T : rows = keys (4 m-tiles), cols = 16 queries ----
        f32x4 s[4];
        #pragma unroll
        for (int k4 = 0; k4 < 4; ++k4) s[k4] = (f32x4){0.f, 0.f, 0.f, 0.f};
        #pragma unroll
        for (int h = 0; h < 2; ++h)
            #pragma unroll
            for (int k4 = 0; k4 < 4; ++k4) {
                bf16x8 kf = *(const bf16x8*)&ks[k4 * 16 + l16][h * 32 + quad * 8];
                s[k4] = __builtin_amdgcn_mfma_f32_16x16x32_bf16(kf, qf[h], s[k4], 0, 0, 0);
            }
        __syncthreads();   // all waves' ks reads done before P overwrites region

        // ---- exp2, deferred row-sum, P store: 4 consecutive keys -> one b64 ----
        #pragma unroll
        for (int k4 = 0; k4 < 4; ++k4) {
            bf16x4 pk;
            #pragma unroll
            for (int r = 0; r < 4; ++r) {
                float p = __ocml_exp2_f32(s[k4][r]);
                pk[r] = (bf16)p;
                lsum += p;
            }
            *(bf16x4*)&ks[w * 16 + l16][k4 * 16 + quad * 4] = pk;
        }

        // ---- O += P . V  (wave-local P read; lgkmcnt orders write->read) ----
        #pragma unroll
        for (int h = 0; h < 2; ++h) {
            bf16x8 pf = *(const bf16x8*)&ks[w * 16 + l16][h * 32 + quad * 8];
            #pragma unroll
            for (int dt = 0; dt < 4; ++dt) {
                bf16x8 vf = *(const bf16x8*)&vt[dt * 16 + l16][h * 32 + quad * 8];
                acc[dt] = __builtin_amdgcn_mfma_f32_16x16x32_bf16(pf, vf, acc[dt], 0, 0, 0);
            }
        }
    }

    // ---- epilogue: reduce l across quads; O = acc / l ----
    {
        float v = lsum;
        v += __shfl_xor(v, 16);
        v += __shfl_xor(v, 32);
        lsum = v;
    }
    #pragma unroll
    for (int r = 0; r < 4; ++r) {
        float lv  = __shfl(lsum, quad * 16 + quad * 4 + r); // lane holding query quad*4+r
        float inv = 1.0f / lv;
        int q = qbase + quad * 4 + r;
        float* op = O + base + (size_t)q * D_;
        #pragma unroll
        for (int dt = 0; dt < 4; ++dt)
            op[dt * 16 + l16] = acc[dt][r] * inv;
    }
}

extern "C" void kernel_launch(void* const* d_in, const int* in_sizes, int n_in,
                              void* d_out, int out_size, void* d_ws, size_t ws_size,
                              hipStream_t stream)
{
    const float* Q    = (const float*)d_in[0];
    const float* K    = (const float*)d_in[1];
    const float* V    = (const float*)d_in[2];
    const int*   mask = (const int*)d_in[3];
    float*       O    = (float*)d_out;

    dim3 grid(8 * 16 * QT);   // 2048 blocks = 8 per CU
    fa_fwd<<<grid, 256, 0, stream>>>(Q, K, V, mask, O);
}

// Round 4
// 188.193 us; speedup vs baseline: 1.0646x; 1.0646x over previous
//
#include <hip/hip_runtime.h>
#include <hip/hip_bf16.h>

typedef __bf16 bf16;
typedef __bf16 bf16x4 __attribute__((ext_vector_type(4)));
typedef __bf16 bf16x8 __attribute__((ext_vector_type(8)));
typedef float  f32x16 __attribute__((ext_vector_type(16)));

extern "C" __device__ float __ocml_exp2_f32(float);

#define S_  1024
#define D_  64
#define BQ  128          // 4 waves x 32 queries
#define BK  64
#define KT  (S_/BK)      // 16
#define QT  (S_/BQ)      // 8
#define LD  72           // bf16 stride: 144B rows, 16B-aligned (b128-safe)

#define ZERO16 {0.f,0.f,0.f,0.f,0.f,0.f,0.f,0.f,0.f,0.f,0.f,0.f,0.f,0.f,0.f,0.f}

// S^T = K.Q^T and O^T = V^T.P^T with 32x32x16 MFMA.
// A layout: m=lane&31, k=(lane>>5)*8+j.  B: n=lane&31, k=(lane>>5)*8+j.
// C/D: col(n)=lane&31, row(m)=(reg&3)+8*(reg>>2)+4*(lane>>5).
// q = lane&31 in BOTH C layouts -> lsum stays in-lane.
__global__ __launch_bounds__(256, 4)
void fa_fwd(const float* __restrict__ Q, const float* __restrict__ K,
            const float* __restrict__ V, const int* __restrict__ mask,
            float* __restrict__ O)
{
    __shared__ bf16 ks[BK][LD];      // K tile [key][d]
    __shared__ bf16 vt[D_][LD];      // V^T tile [d][key]
    __shared__ bf16 ps[4][32][LD];   // per-wave P^T as [q][key]

    const int tid  = threadIdx.x;
    const int lane = tid & 63;
    const int w    = tid >> 6;
    const int l32  = lane & 31;
    const int hi   = lane >> 5;

    // XCD swizzle: the 8 q-tiles of one bh share an XCD (bid%8 round-robin)
    const int bid   = blockIdx.x;
    const int xcd   = bid & 7;
    const int rnd   = bid >> 3;                 // 0..127
    const int qtile = rnd & 7;
    const int bh    = ((rnd >> 3) << 3) | xcd;  // 0..127
    const int b     = bh >> 4;                  // H=16
    const size_t base = (size_t)bh * (S_ * D_);
    const int qW = qtile * BQ + w * 32;

    // fold 1/sqrt(64) and log2(e) into Q; mask[b] -> scale 0 (uniform softmax)
    const float qscale = (mask[b] != 0) ? 0.0f : 0.1803368801111204f;

    // ---- Q B-fragments, direct from global: B[k=d][n=q=l32] ----
    bf16x8 qf[4];
    {
        const float* qp = Q + base + (size_t)(qW + l32) * D_ + hi * 8;
        #pragma unroll
        for (int kc = 0; kc < 4; ++kc) {
            float4 a = *(const float4*)(qp + kc * 16);
            float4 c = *(const float4*)(qp + kc * 16 + 4);
            bf16x8 f;
            f[0] = (bf16)(a.x * qscale); f[1] = (bf16)(a.y * qscale);
            f[2] = (bf16)(a.z * qscale); f[3] = (bf16)(a.w * qscale);
            f[4] = (bf16)(c.x * qscale); f[5] = (bf16)(c.y * qscale);
            f[6] = (bf16)(c.z * qscale); f[7] = (bf16)(c.w * qscale);
            qf[kc] = f;
        }
    }

    f32x16 o0 = ZERO16, o1 = ZERO16;   // O^T rows d=0..31 / 32..63, col q=l32
    float lsum = 0.f;

    const int vkq = (tid >> 2) & 15;   // V transpose: 4-key group
    const int vc4 = (tid & 3) + 4 * w; // d-chunk
    const float4* gk = (const float4*)(K + base);
    const float4* gv = (const float4*)(V + base);
    bf16* psw = &ps[w][l32][0];        // this lane's P^T row (q = l32)

    for (int kt = 0; kt < KT; ++kt) {
        // ---- register-prefetch K,V tile (VMEM overlaps prior compute) ----
        float4 kr[4], vr[4];
        #pragma unroll
        for (int it = 0; it < 4; ++it)
            kr[it] = gk[kt * 1024 + it * 256 + tid];
        #pragma unroll
        for (int r = 0; r < 4; ++r)
            vr[r] = gv[kt * 1024 + (vkq * 4 + r) * 16 + vc4];

        __syncthreads();               // prior tile reads done
        #pragma unroll
        for (int it = 0; it < 4; ++it) {
            int i = it * 256 + tid;
            int row = i >> 4, c4 = i & 15;
            bf16x4 hk = {(bf16)kr[it].x, (bf16)kr[it].y, (bf16)kr[it].z, (bf16)kr[it].w};
            *(bf16x4*)&ks[row][c4 * 4] = hk;
        }
        {
            bf16x4 t0 = {(bf16)vr[0].x, (bf16)vr[1].x, (bf16)vr[2].x, (bf16)vr[3].x};
            bf16x4 t1 = {(bf16)vr[0].y, (bf16)vr[1].y, (bf16)vr[2].y, (bf16)vr[3].y};
            bf16x4 t2 = {(bf16)vr[0].z, (bf16)vr[1].z, (bf16)vr[2].z, (bf16)vr[3].z};
            bf16x4 t3 = {(bf16)vr[0].w, (bf16)vr[1].w, (bf16)vr[2].w, (bf16)vr[3].w};
            *(bf16x4*)&vt[vc4 * 4 + 0][vkq * 4] = t0;
            *(bf16x4*)&vt[vc4 * 4 + 1][vkq * 4] = t1;
            *(bf16x4*)&vt[vc4 * 4 + 2][vkq * 4] = t2;
            *(bf16x4*)&vt[vc4 * 4 + 3][vkq * 4] = t3;
        }
        __syncthreads();

        // ---- S^T = K . Q^T : m = 64 keys (2 tiles), n = 32 queries ----
        f32x16 s0 = ZERO16, s1 = ZERO16;
        #pragma unroll
        for (int kc = 0; kc < 4; ++kc) {
            bf16x8 k0 = *(const bf16x8*)&ks[l32][kc * 16 + hi * 8];
            bf16x8 k1 = *(const bf16x8*)&ks[32 + l32][kc * 16 + hi * 8];
            s0 = __builtin_amdgcn_mfma_f32_32x32x16_bf16(k0, qf[kc], s0, 0, 0, 0);
            s1 = __builtin_amdgcn_mfma_f32_32x32x16_bf16(k1, qf[kc], s1, 0, 0, 0);
        }

        // ---- exp2, deferred row-sum, P^T store (reg&3 = 4 consecutive keys) ----
        #pragma unroll
        for (int g = 0; g < 4; ++g) {
            bf16x4 p0, p1;
            #pragma unroll
            for (int r = 0; r < 4; ++r) {
                float e0 = __ocml_exp2_f32(s0[g * 4 + r]);
                float e1 = __ocml_exp2_f32(s1[g * 4 + r]);
                lsum += e0 + e1;
                p0[r] = (bf16)e0;
                p1[r] = (bf16)e1;
            }
            *(bf16x4*)&psw[g * 8 + hi * 4]      = p0;  // keys  0..31 half
            *(bf16x4*)&psw[32 + g * 8 + hi * 4] = p1;  // keys 32..63 half
        }

        // ---- O^T += V^T . P^T : m = 64 d (2 tiles), k = 64 keys ----
        #pragma unroll
        for (int kc = 0; kc < 4; ++kc) {
            bf16x8 pf = *(const bf16x8*)&psw[kc * 16 + hi * 8];
            bf16x8 v0 = *(const bf16x8*)&vt[l32][kc * 16 + hi * 8];
            bf16x8 v1 = *(const bf16x8*)&vt[32 + l32][kc * 16 + hi * 8];
            o0 = __builtin_amdgcn_mfma_f32_32x32x16_bf16(v0, pf, o0, 0, 0, 0);
            o1 = __builtin_amdgcn_mfma_f32_32x32x16_bf16(v1, pf, o1, 0, 0, 0);
        }
    }

    // ---- epilogue: l lives at the same lane (q=l32); one cross-half add ----
    lsum += __shfl_xor(lsum, 32);
    float inv = 1.0f / lsum;
    float* op = O + base + (size_t)(qW + l32) * D_ + hi * 4;
    #pragma unroll
    for (int g = 0; g < 4; ++g) {
        float4 a = { o0[g * 4 + 0] * inv, o0[g * 4 + 1] * inv,
                     o0[g * 4 + 2] * inv, o0[g * 4 + 3] * inv };
        *(float4*)(op + g * 8) = a;            // d = 4hi + 8g + r
        float4 c = { o1[g * 4 + 0] * inv, o1[g * 4 + 1] * inv,
                     o1[g * 4 + 2] * inv, o1[g * 4 + 3] * inv };
        *(float4*)(op + 32 + g * 8) = c;       // d = 32 + 4hi + 8g + r
    }
}

extern "C" void kernel_launch(void* const* d_in, const int* in_sizes, int n_in,
                              void* d_out, int out_size, void* d_ws, size_t ws_size,
                              hipStream_t stream)
{
    const float* Q    = (const float*)d_in[0];
    const float* K    = (const float*)d_in[1];
    const float* V    = (const float*)d_in[2];
    const int*   mask = (const int*)d_in[3];
    float*       O    = (float*)d_out;

    dim3 grid(8 * 16 * QT);   // 1024 blocks = 4 per CU
    fa_fwd<<<grid, 256, 0, stream>>>(Q, K, V, mask, O);
}

// Round 5
// 164.926 us; speedup vs baseline: 1.2148x; 1.1411x over previous
//
#include <hip/hip_runtime.h>
#include <hip/hip_bf16.h>

typedef __bf16 bf16;
typedef __bf16 bf16x4 __attribute__((ext_vector_type(4)));
typedef __bf16 bf16x8 __attribute__((ext_vector_type(8)));
typedef float  f32x16 __attribute__((ext_vector_type(16)));

#define S_  1024
#define D_  64
#define BQ  128          // 4 waves x 32 queries
#define BK  64
#define KT  (S_/BK)      // 16
#define QT  (S_/BQ)      // 8
#define LD  72           // bf16 stride: 144B rows, 16B-aligned (b128-safe)

#define ZERO16 {0.f,0.f,0.f,0.f,0.f,0.f,0.f,0.f,0.f,0.f,0.f,0.f,0.f,0.f,0.f,0.f}

// S^T = K.Q^T and O^T = V^T.P^T with 32x32x16 MFMA.
// A layout: m=lane&31, k=(lane>>5)*8+j.  B: n=lane&31, k=(lane>>5)*8+j.
// C/D: col(n)=lane&31, row(m)=(reg&3)+8*(reg>>2)+4*(lane>>5).
// q = lane&31 in BOTH C layouts -> lsum stays in-lane.
__global__ __launch_bounds__(256, 4)
void fa_fwd(const float* __restrict__ Q, const float* __restrict__ K,
            const float* __restrict__ V, const int* __restrict__ mask,
            float* __restrict__ O)
{
    __shared__ bf16 ks[BK][LD];      // K tile [key][d]
    __shared__ bf16 vt[D_][LD];      // V^T tile [d][key]
    __shared__ bf16 ps[4][32][LD];   // per-wave P^T as [q][key]

    const int tid  = threadIdx.x;
    const int lane = tid & 63;
    const int w    = tid >> 6;
    const int l32  = lane & 31;
    const int hi   = lane >> 5;

    // XCD swizzle: the 8 q-tiles of one bh share an XCD (bid%8 round-robin)
    const int bid   = blockIdx.x;
    const int xcd   = bid & 7;
    const int rnd   = bid >> 3;                 // 0..127
    const int qtile = rnd & 7;
    const int bh    = ((rnd >> 3) << 3) | xcd;  // 0..127
    const int b     = bh >> 4;                  // H=16
    const size_t base = (size_t)bh * (S_ * D_);
    const int qW = qtile * BQ + w * 32;

    // fold 1/sqrt(64) and log2(e) into Q; mask[b] -> scale 0 (uniform softmax)
    const float qscale = (mask[b] != 0) ? 0.0f : 0.1803368801111204f;

    // ---- Q B-fragments, direct from global: B[k=d][n=q=l32] ----
    bf16x8 qf[4];
    {
        const float* qp = Q + base + (size_t)(qW + l32) * D_ + hi * 8;
        #pragma unroll
        for (int kc = 0; kc < 4; ++kc) {
            float4 a = *(const float4*)(qp + kc * 16);
            float4 c = *(const float4*)(qp + kc * 16 + 4);
            bf16x8 f;
            f[0] = (bf16)(a.x * qscale); f[1] = (bf16)(a.y * qscale);
            f[2] = (bf16)(a.z * qscale); f[3] = (bf16)(a.w * qscale);
            f[4] = (bf16)(c.x * qscale); f[5] = (bf16)(c.y * qscale);
            f[6] = (bf16)(c.z * qscale); f[7] = (bf16)(c.w * qscale);
            qf[kc] = f;
        }
    }

    f32x16 o0 = ZERO16, o1 = ZERO16;   // O^T rows d=0..31 / 32..63, col q=l32
    float lsum = 0.f;

    const int vkq = (tid >> 2) & 15;   // V transpose: 4-key group
    const int vc4 = (tid & 3) + 4 * w; // d-chunk
    const float4* gk = (const float4*)(K + base);
    const float4* gv = (const float4*)(V + base);
    bf16* psw = &ps[w][l32][0];        // this lane's P^T row (q = l32)

    // ---- prologue: prefetch tile 0 ----
    float4 kr[4], vr[4];
    #pragma unroll
    for (int it = 0; it < 4; ++it)
        kr[it] = gk[it * 256 + tid];
    #pragma unroll
    for (int r = 0; r < 4; ++r)
        vr[r] = gv[(vkq * 4 + r) * 16 + vc4];

    for (int kt = 0; kt < KT; ++kt) {
        __syncthreads();               // prior tile's LDS reads done
        // ---- stage K tile from regs: row-major bf16, b64 writes ----
        #pragma unroll
        for (int it = 0; it < 4; ++it) {
            int i = it * 256 + tid;
            int row = i >> 4, c4 = i & 15;
            bf16x4 hk = {(bf16)kr[it].x, (bf16)kr[it].y, (bf16)kr[it].z, (bf16)kr[it].w};
            *(bf16x4*)&ks[row][c4 * 4] = hk;
        }
        // ---- stage V^T from regs: in-register 4x4 pack ----
        {
            bf16x4 t0 = {(bf16)vr[0].x, (bf16)vr[1].x, (bf16)vr[2].x, (bf16)vr[3].x};
            bf16x4 t1 = {(bf16)vr[0].y, (bf16)vr[1].y, (bf16)vr[2].y, (bf16)vr[3].y};
            bf16x4 t2 = {(bf16)vr[0].z, (bf16)vr[1].z, (bf16)vr[2].z, (bf16)vr[3].z};
            bf16x4 t3 = {(bf16)vr[0].w, (bf16)vr[1].w, (bf16)vr[2].w, (bf16)vr[3].w};
            *(bf16x4*)&vt[vc4 * 4 + 0][vkq * 4] = t0;
            *(bf16x4*)&vt[vc4 * 4 + 1][vkq * 4] = t1;
            *(bf16x4*)&vt[vc4 * 4 + 2][vkq * 4] = t2;
            *(bf16x4*)&vt[vc4 * 4 + 3][vkq * 4] = t3;
        }
        __syncthreads();

        // ---- issue next tile's loads NOW: latency hidden under compute ----
        {
            int ktn = (kt + 1 < KT) ? (kt + 1) : kt;   // clamped (redundant last iter)
            #pragma unroll
            for (int it = 0; it < 4; ++it)
                kr[it] = gk[ktn * 1024 + it * 256 + tid];
            #pragma unroll
            for (int r = 0; r < 4; ++r)
                vr[r] = gv[ktn * 1024 + (vkq * 4 + r) * 16 + vc4];
        }

        // ---- S^T = K . Q^T : m = 64 keys (2 tiles), n = 32 queries ----
        f32x16 s0 = ZERO16, s1 = ZERO16;
        #pragma unroll
        for (int kc = 0; kc < 4; ++kc) {
            bf16x8 k0 = *(const bf16x8*)&ks[l32][kc * 16 + hi * 8];
            bf16x8 k1 = *(const bf16x8*)&ks[32 + l32][kc * 16 + hi * 8];
            s0 = __builtin_amdgcn_mfma_f32_32x32x16_bf16(k0, qf[kc], s0, 0, 0, 0);
            s1 = __builtin_amdgcn_mfma_f32_32x32x16_bf16(k1, qf[kc], s1, 0, 0, 0);
        }

        // ---- raw v_exp_f32, deferred row-sum, P^T store (4 consecutive keys) ----
        #pragma unroll
        for (int g = 0; g < 4; ++g) {
            bf16x4 p0, p1;
            #pragma unroll
            for (int r = 0; r < 4; ++r) {
                float e0 = __builtin_amdgcn_exp2f(s0[g * 4 + r]);
                float e1 = __builtin_amdgcn_exp2f(s1[g * 4 + r]);
                lsum += e0 + e1;
                p0[r] = (bf16)e0;
                p1[r] = (bf16)e1;
            }
            *(bf16x4*)&psw[g * 8 + hi * 4]      = p0;  // keys  0..31 half
            *(bf16x4*)&psw[32 + g * 8 + hi * 4] = p1;  // keys 32..63 half
        }

        // ---- O^T += V^T . P^T : m = 64 d (2 tiles), k = 64 keys ----
        #pragma unroll
        for (int kc = 0; kc < 4; ++kc) {
            bf16x8 pf = *(const bf16x8*)&psw[kc * 16 + hi * 8];
            bf16x8 v0 = *(const bf16x8*)&vt[l32][kc * 16 + hi * 8];
            bf16x8 v1 = *(const bf16x8*)&vt[32 + l32][kc * 16 + hi * 8];
            o0 = __builtin_amdgcn_mfma_f32_32x32x16_bf16(v0, pf, o0, 0, 0, 0);
            o1 = __builtin_amdgcn_mfma_f32_32x32x16_bf16(v1, pf, o1, 0, 0, 0);
        }
    }

    // ---- epilogue: l lives at the same lane (q=l32); one cross-half add ----
    lsum += __shfl_xor(lsum, 32);
    float inv = 1.0f / lsum;
    float* op = O + base + (size_t)(qW + l32) * D_ + hi * 4;
    #pragma unroll
    for (int g = 0; g < 4; ++g) {
        float4 a = { o0[g * 4 + 0] * inv, o0[g * 4 + 1] * inv,
                     o0[g * 4 + 2] * inv, o0[g * 4 + 3] * inv };
        *(float4*)(op + g * 8) = a;            // d = 4hi + 8g + r
        float4 c = { o1[g * 4 + 0] * inv, o1[g * 4 + 1] * inv,
                     o1[g * 4 + 2] * inv, o1[g * 4 + 3] * inv };
        *(float4*)(op + 32 + g * 8) = c;       // d = 32 + 4hi + 8g + r
    }
}

extern "C" void kernel_launch(void* const* d_in, const int* in_sizes, int n_in,
                              void* d_out, int out_size, void* d_ws, size_t ws_size,
                              hipStream_t stream)
{
    const float* Q    = (const float*)d_in[0];
    const float* K    = (const float*)d_in[1];
    const float* V    = (const float*)d_in[2];
    const int*   mask = (const int*)d_in[3];
    float*       O    = (float*)d_out;

    dim3 grid(8 * 16 * QT);   // 1024 blocks = 4 per CU
    fa_fwd<<<grid, 256, 0, stream>>>(Q, K, V, mask, O);
}

// Round 7
// 150.011 us; speedup vs baseline: 1.3356x; 1.0994x over previous
//
#include <hip/hip_runtime.h>
#include <hip/hip_bf16.h>

typedef __bf16 bf16;
typedef __bf16 bf16x4 __attribute__((ext_vector_type(4)));
typedef __bf16 bf16x8 __attribute__((ext_vector_type(8)));
typedef float  f32x16 __attribute__((ext_vector_type(16)));

#define S_  1024
#define D_  64
#define BQ  256          // 4 waves x 64 queries
#define BK  64
#define KT  (S_/BK)      // 16
#define QT  (S_/BQ)      // 4
#define LD  72           // bf16 stride: 144B rows, 16B-aligned

#define ZERO16 {0.f,0.f,0.f,0.f,0.f,0.f,0.f,0.f,0.f,0.f,0.f,0.f,0.f,0.f,0.f,0.f}

// S^T = K.Q^T ; O^T = V^T.P^T  with 32x32x16 MFMA, n=64 queries per wave.
// A/B: m|n=lane&31, k=(lane>>5)*8+j.  C/D: col=lane&31, row=(reg&3)+8*(reg>>2)+4*(lane>>5).
//
// KEY-PERMUTATION TRICK (replaces any P layout shuffle): softmax+PV contract
// over keys, so any key permutation applied consistently to (S rows, V^T cols)
// is legal. Store V key kk at LDS column rho(kk), rho = swap bits 2<->3 of key
// index. Then the PV B-frag for chunk kc is concat(p[2*(kc&1)], p[2*(kc&1)+1])
// of the lane's OWN exp'd QK output registers: no cross-lane exchange at all.
__global__ __launch_bounds__(256, 2)
void fa_fwd(const float* __restrict__ Q, const float* __restrict__ K,
            const float* __restrict__ V, const int* __restrict__ mask,
            float* __restrict__ O)
{
    __shared__ bf16 ks[2][BK][LD];   // double-buffered K tile [key][d]
    __shared__ bf16 vt[2][D_][LD];   // double-buffered V^T tile [d][rho(key)]

    const int tid  = threadIdx.x;
    const int lane = tid & 63;
    const int w    = tid >> 6;
    const int l32  = lane & 31;
    const int hi   = lane >> 5;

    // XCD swizzle: 4 q-tiles of one bh on one XCD (bid%8 round-robin)
    const int bid   = blockIdx.x;
    const int xcd   = bid & 7;
    const int rnd   = bid >> 3;                 // 0..63
    const int qtile = rnd & 3;
    const int bh    = ((rnd >> 2) << 3) | xcd;  // 0..127
    const int b     = bh >> 4;                  // H=16
    const size_t base = (size_t)bh * (S_ * D_);
    const int qW = qtile * BQ + w * 64;

    const float qscale = (mask[b] != 0) ? 0.0f : 0.1803368801111204f; // log2e/8

    // ---- Q B-fragments for 2 n-tiles: B[k=d][n=q] ----
    bf16x8 qf[2][4];
    #pragma unroll
    for (int nt = 0; nt < 2; ++nt) {
        const float* qp = Q + base + (size_t)(qW + nt * 32 + l32) * D_ + hi * 8;
        #pragma unroll
        for (int kc = 0; kc < 4; ++kc) {
            float4 a = *(const float4*)(qp + kc * 16);
            float4 c = *(const float4*)(qp + kc * 16 + 4);
            bf16x8 f;
            f[0] = (bf16)(a.x * qscale); f[1] = (bf16)(a.y * qscale);
            f[2] = (bf16)(a.z * qscale); f[3] = (bf16)(a.w * qscale);
            f[4] = (bf16)(c.x * qscale); f[5] = (bf16)(c.y * qscale);
            f[6] = (bf16)(c.z * qscale); f[7] = (bf16)(c.w * qscale);
            qf[nt][kc] = f;
        }
    }

    f32x16 o[2][2];                  // [d-tile][n-tile]
    #pragma unroll
    for (int dm = 0; dm < 2; ++dm)
        #pragma unroll
        for (int nt = 0; nt < 2; ++nt) o[dm][nt] = (f32x16)ZERO16;
    float lsum[2] = {0.f, 0.f};

    const int vkq = (tid >> 2) & 15;    // V transpose: 4-key group (natural)
    const int vkp = (vkq & 12) | ((vkq & 1) << 1) | ((vkq >> 1) & 1); // rho on group
    const int vc4 = (tid & 3) + 4 * w;  // d-chunk
    const float4* gk = (const float4*)(K + base);
    const float4* gv = (const float4*)(V + base);

    // prologue: prefetch tile 0
    float4 kr[4], vr[4];
    #pragma unroll
    for (int it = 0; it < 4; ++it) kr[it] = gk[it * 256 + tid];
    #pragma unroll
    for (int r = 0; r < 4; ++r)    vr[r]  = gv[(vkq * 4 + r) * 16 + vc4];

    // exp of one 32-row S-tile; fA = chunk (2mt), fB = chunk (2mt+1), own regs only
    auto mkpf = [&](const f32x16& sv, bf16x8& fA, bf16x8& fB, float& ls) {
        bf16x8 a, c;
        #pragma unroll
        for (int i = 0; i < 8; ++i) {
            float e0 = __builtin_amdgcn_exp2f(sv[i]);
            float e1 = __builtin_amdgcn_exp2f(sv[8 + i]);
            ls += e0 + e1;
            a[i] = (bf16)e0;
            c[i] = (bf16)e1;
        }
        fA = a; fB = c;
    };

    for (int kt = 0; kt < KT; ++kt) {
        bf16 (*ksb)[LD] = ks[kt & 1];
        bf16 (*vtb)[LD] = vt[kt & 1];

        // ---- stage K tile from regs (natural key rows) ----
        #pragma unroll
        for (int it = 0; it < 4; ++it) {
            int i = it * 256 + tid;
            int row = i >> 4, c4 = i & 15;
            bf16x4 hk = {(bf16)kr[it].x, (bf16)kr[it].y, (bf16)kr[it].z, (bf16)kr[it].w};
            *(bf16x4*)&ksb[row][c4 * 4] = hk;
        }
        // ---- stage V^T from regs at rho-permuted columns ----
        {
            bf16x4 t0 = {(bf16)vr[0].x, (bf16)vr[1].x, (bf16)vr[2].x, (bf16)vr[3].x};
            bf16x4 t1 = {(bf16)vr[0].y, (bf16)vr[1].y, (bf16)vr[2].y, (bf16)vr[3].y};
            bf16x4 t2 = {(bf16)vr[0].z, (bf16)vr[1].z, (bf16)vr[2].z, (bf16)vr[3].z};
            bf16x4 t3 = {(bf16)vr[0].w, (bf16)vr[1].w, (bf16)vr[2].w, (bf16)vr[3].w};
            *(bf16x4*)&vtb[vc4 * 4 + 0][vkp * 4] = t0;
            *(bf16x4*)&vtb[vc4 * 4 + 1][vkp * 4] = t1;
            *(bf16x4*)&vtb[vc4 * 4 + 2][vkp * 4] = t2;
            *(bf16x4*)&vtb[vc4 * 4 + 3][vkp * 4] = t3;
        }
        // ---- prefetch next tile (latency under this tile's compute) ----
        {
            int ktn = (kt + 1 < KT) ? (kt + 1) : kt;
            #pragma unroll
            for (int it = 0; it < 4; ++it) kr[it] = gk[ktn * 1024 + it * 256 + tid];
            #pragma unroll
            for (int r = 0; r < 4; ++r)    vr[r]  = gv[ktn * 1024 + (vkq * 4 + r) * 16 + vc4];
        }
        __syncthreads();   // single barrier per tile (safe with double buffer)

        // ---- S^T = K.Q^T : 2 m-tiles (keys) x 2 n-tiles (queries) ----
        f32x16 s00 = ZERO16, s01 = ZERO16, s10 = ZERO16, s11 = ZERO16;
        #pragma unroll
        for (int kc = 0; kc < 4; ++kc) {
            bf16x8 k0 = *(const bf16x8*)&ksb[l32][kc * 16 + hi * 8];
            bf16x8 k1 = *(const bf16x8*)&ksb[32 + l32][kc * 16 + hi * 8];
            s00 = __builtin_amdgcn_mfma_f32_32x32x16_bf16(k0, qf[0][kc], s00, 0, 0, 0);
            s01 = __builtin_amdgcn_mfma_f32_32x32x16_bf16(k0, qf[1][kc], s01, 0, 0, 0);
            s10 = __builtin_amdgcn_mfma_f32_32x32x16_bf16(k1, qf[0][kc], s10, 0, 0, 0);
            s11 = __builtin_amdgcn_mfma_f32_32x32x16_bf16(k1, qf[1][kc], s11, 0, 0, 0);
        }

        // ---- exp -> PV B-frags, all in-lane (key-permutation trick) ----
        bf16x8 pf[4][2];                 // [kc][nt]
        mkpf(s00, pf[0][0], pf[1][0], lsum[0]);
        mkpf(s01, pf[0][1], pf[1][1], lsum[1]);
        mkpf(s10, pf[2][0], pf[3][0], lsum[0]);
        mkpf(s11, pf[2][1], pf[3][1], lsum[1]);

        // ---- O^T += V^T.P^T ----
        #pragma unroll
        for (int kc = 0; kc < 4; ++kc) {
            bf16x8 v0 = *(const bf16x8*)&vtb[l32][kc * 16 + hi * 8];
            bf16x8 v1 = *(const bf16x8*)&vtb[32 + l32][kc * 16 + hi * 8];
            o[0][0] = __builtin_amdgcn_mfma_f32_32x32x16_bf16(v0, pf[kc][0], o[0][0], 0, 0, 0);
            o[0][1] = __builtin_amdgcn_mfma_f32_32x32x16_bf16(v0, pf[kc][1], o[0][1], 0, 0, 0);
            o[1][0] = __builtin_amdgcn_mfma_f32_32x32x16_bf16(v1, pf[kc][0], o[1][0], 0, 0, 0);
            o[1][1] = __builtin_amdgcn_mfma_f32_32x32x16_bf16(v1, pf[kc][1], o[1][1], 0, 0, 0);
        }
    }

    // ---- epilogue: lane holds half the keys' sum; one cross-half add ----
    #pragma unroll
    for (int nt = 0; nt < 2; ++nt) {
        float lv = lsum[nt] + __shfl_xor(lsum[nt], 32);
        float inv = 1.0f / lv;
        float* op = O + base + (size_t)(qW + nt * 32 + l32) * D_ + hi * 4;
        #pragma unroll
        for (int g = 0; g < 4; ++g) {
            float4 a = { o[0][nt][g * 4 + 0] * inv, o[0][nt][g * 4 + 1] * inv,
                         o[0][nt][g * 4 + 2] * inv, o[0][nt][g * 4 + 3] * inv };
            *(float4*)(op + g * 8) = a;           // d = 4hi + 8g + r
            float4 c = { o[1][nt][g * 4 + 0] * inv, o[1][nt][g * 4 + 1] * inv,
                         o[1][nt][g * 4 + 2] * inv, o[1][nt][g * 4 + 3] * inv };
            *(float4*)(op + 32 + g * 8) = c;      // d = 32 + 4hi + 8g + r
        }
    }
}

extern "C" void kernel_launch(void* const* d_in, const int* in_sizes, int n_in,
                              void* d_out, int out_size, void* d_ws, size_t ws_size,
                              hipStream_t stream)
{
    const float* Q    = (const float*)d_in[0];
    const float* K    = (const float*)d_in[1];
    const float* V    = (const float*)d_in[2];
    const int*   mask = (const int*)d_in[3];
    float*       O    = (float*)d_out;

    dim3 grid(8 * 16 * QT);   // 512 blocks = 2 per CU
    fa_fwd<<<grid, 256, 0, stream>>>(Q, K, V, mask, O);
}